// Round 11
// baseline (397.971 us; speedup 1.0000x reference)
//
#include <hip/hip_runtime.h>

#define NN 100000
#define EE 1600000
#define NB 391          // buckets of 256 dst nodes: ceil(100000/256)
#define CHUNK 2048

typedef __attribute__((ext_vector_type(8))) short bf16x8;
typedef __attribute__((ext_vector_type(4))) float f32x4;

union BV8 { bf16x8 v; uint4 u; };

static __device__ __forceinline__ unsigned short f2bf(float f) {
  unsigned u = __float_as_uint(f);
  u += 0x7fffu + ((u >> 16) & 1u);   // round-to-nearest-even
  return (unsigned short)(u >> 16);
}
static __device__ __forceinline__ float bf2f(unsigned short s) {
  return __uint_as_float(((unsigned)s) << 16);
}
// HW packed f32->bf16 (no builtin on gfx950)
static __device__ __forceinline__ unsigned cvt_pk_bf16(float a, float b) {
  unsigned r;
  asm("v_cvt_pk_bf16_f32 %0, %1, %2" : "=v"(r) : "v"(a), "v"(b));
  return r;
}
static __device__ __forceinline__ float bflo(unsigned u) { return __uint_as_float(u << 16); }
static __device__ __forceinline__ float bfhi(unsigned u) { return __uint_as_float(u & 0xffff0000u); }

// ---------------- CSR build: two-level counting sort (4B packed pairs) ----------------

__global__ void zero_aux(int* __restrict__ bcnt, int* __restrict__ bfill) {
  int i = blockIdx.x * 256 + threadIdx.x;
  if (i < NB * 16) { bcnt[i] = 0; bfill[i] = 0; }
}

__launch_bounds__(256)
__global__ void bucket_hist(const int* __restrict__ dst, int* __restrict__ bcnt) {
  __shared__ int hist[NB];
  int tid = threadIdx.x;
  for (int i = tid; i < NB; i += 256) hist[i] = 0;
  __syncthreads();
  int e0 = blockIdx.x * CHUNK;
  int n = min(CHUNK, EE - e0);
  for (int i = tid; i < n; i += 256) atomicAdd(&hist[dst[e0 + i] >> 8], 1);
  __syncthreads();
  for (int i = tid; i < NB; i += 256) {
    int c = hist[i];
    if (c) atomicAdd(&bcnt[i * 16], c);
  }
}

__launch_bounds__(256)
__global__ void bucket_scan(const int* __restrict__ bcnt, int* __restrict__ bOffC,
                            int* __restrict__ offsets) {
  __shared__ int wpart[4];
  __shared__ int carryS;
  int tid = threadIdx.x, lane = tid & 63, w = tid >> 6;
  if (tid == 0) carryS = 0;
  __syncthreads();
  for (int base = 0; base < NB; base += 256) {
    int i = base + tid;
    int v = (i < NB) ? bcnt[i * 16] : 0;
    int x = v;
    #pragma unroll
    for (int d = 1; d < 64; d <<= 1) { int y = __shfl_up(x, d); if (lane >= d) x += y; }
    if (lane == 63) wpart[w] = x;
    __syncthreads();
    int wbase = 0;
    #pragma unroll
    for (int k = 0; k < 3; ++k) if (k < w) wbase += wpart[k];
    int tot = wpart[0] + wpart[1] + wpart[2] + wpart[3];
    int carry = carryS;
    if (i < NB) bOffC[i] = carry + wbase + x - v;
    __syncthreads();
    if (tid == 0) carryS = carry + tot;
    __syncthreads();
  }
  if (tid == 0) offsets[NN] = EE + NN;
}

__launch_bounds__(256)
__global__ void bucket_scatter(const int* __restrict__ ei, const int* __restrict__ bOffC,
                               int* __restrict__ bfill, unsigned* __restrict__ pairs) {
  __shared__ int hist[NB];
  __shared__ int lofs[NB];
  __shared__ int resv[NB];
  __shared__ unsigned stage[CHUNK];
  __shared__ unsigned short stageB[CHUNK];
  __shared__ int wpart[4];
  int tid = threadIdx.x, lane = tid & 63, w = tid >> 6;
  int e0 = blockIdx.x * CHUNK;
  int n = min(CHUNK, EE - e0);
  for (int i = tid; i < NB; i += 256) hist[i] = 0;
  __syncthreads();

  int s[8], d[8], lp[8], bk[8];
  #pragma unroll
  for (int q = 0; q < 8; ++q) {
    int i = q * 256 + tid;
    if (i < n) {
      s[q] = ei[e0 + i];
      d[q] = ei[EE + e0 + i];
      bk[q] = d[q] >> 8;
      lp[q] = atomicAdd(&hist[bk[q]], 1);
    }
  }
  __syncthreads();

  int carry = 0;
  for (int base = 0; base < NB; base += 256) {
    int i = base + tid;
    int v = (i < NB) ? hist[i] : 0;
    int x = v;
    #pragma unroll
    for (int dd = 1; dd < 64; dd <<= 1) { int y = __shfl_up(x, dd); if (lane >= dd) x += y; }
    if (lane == 63) wpart[w] = x;
    __syncthreads();
    int wbase = 0;
    #pragma unroll
    for (int k = 0; k < 3; ++k) if (k < w) wbase += wpart[k];
    int tot = wpart[0] + wpart[1] + wpart[2] + wpart[3];
    if (i < NB) lofs[i] = carry + wbase + x - v;
    __syncthreads();
    carry += tot;
  }

  #pragma unroll
  for (int q = 0; q < 8; ++q) {
    int i = q * 256 + tid;
    if (i < n) {
      int p = lofs[bk[q]] + lp[q];
      stage[p]  = ((unsigned)(d[q] & 255) << 24) | (unsigned)s[q];
      stageB[p] = (unsigned short)bk[q];
    }
  }
  for (int b = tid; b < NB; b += 256) {
    int c = hist[b];
    resv[b] = c ? atomicAdd(&bfill[b * 16], c) : 0;
  }
  __syncthreads();
  for (int i = tid; i < n; i += 256) {
    int b = stageB[i];
    pairs[(size_t)bOffC[b] + resv[b] + (i - lofs[b])] = stage[i];
  }
}

__launch_bounds__(256)
__global__ void build_csr(const unsigned* __restrict__ pairs, const int* __restrict__ bOffC,
                          const int* __restrict__ bcnt, int* __restrict__ offsets,
                          int* __restrict__ srcs) {
  __shared__ int deg[256];
  __shared__ int intra[256];
  __shared__ int fil[256];
  __shared__ int wpart[4];
  int b = blockIdx.x, tid = threadIdx.x;
  int n0 = b << 8;
  int nodes = min(256, NN - n0);
  int ecnt = bcnt[b * 16];
  size_t pbase = (size_t)bOffC[b];
  int cbase = bOffC[b] + n0;
  deg[tid] = 0; fil[tid] = 0;
  __syncthreads();
  for (int i = tid; i < ecnt; i += 256) {
    int ln = (int)(pairs[pbase + i] >> 24);
    atomicAdd(&deg[ln], 1);
  }
  __syncthreads();
  int v = (tid < nodes) ? deg[tid] + 1 : 0;
  int lane = tid & 63, w = tid >> 6;
  int x = v;
  #pragma unroll
  for (int dd = 1; dd < 64; dd <<= 1) { int y = __shfl_up(x, dd); if (lane >= dd) x += y; }
  if (lane == 63) wpart[w] = x;
  __syncthreads();
  int wbase = 0;
  #pragma unroll
  for (int k = 0; k < 3; ++k) if (k < w) wbase += wpart[k];
  int excl = wbase + x - v;
  if (tid < nodes) { intra[tid] = excl; offsets[n0 + tid] = cbase + excl; }
  __syncthreads();
  for (int i = tid; i < ecnt; i += 256) {
    unsigned pd = pairs[pbase + i];
    int ln = (int)(pd >> 24), ss = (int)(pd & 0xFFFFFFu);
    int p = atomicAdd(&fil[ln], 1);
    srcs[cbase + intra[ln] + p] = ss;
  }
  __syncthreads();
  if (tid < nodes) srcs[cbase + intra[tid] + deg[tid]] = n0 + tid;
}

// ---------------- W prep: all 3 layers, fragment-ordered bf16 hi/lo (8 ct tiles) ----------------

__global__ void prep_w3(const float* __restrict__ Wa, const float* __restrict__ Wb,
                        const float* __restrict__ Wc, short* __restrict__ Whi,
                        short* __restrict__ Wlo) {
  int t = blockIdx.x * 256 + threadIdx.x;   // 24 blocks = 6144 threads
  int L = t >> 11;                          // layer
  int tt = t & 2047;
  const float* W = (L == 0) ? Wa : (L == 1) ? Wb : Wc;
  int lane = tt & 63, ct = (tt >> 6) & 7, kt = tt >> 9;
  int l4 = lane & 15, grp = lane >> 4;
  int c = ct * 16 + l4;
  int k0 = kt * 32 + grp * 8;
  bf16x8 hi, lo;
  #pragma unroll
  for (int i = 0; i < 8; ++i) {
    float w = W[(k0 + i) * 128 + c];
    unsigned short h = f2bf(w);
    hi[i] = (short)h;
    lo[i] = (short)f2bf(w - bf2f(h));
  }
  size_t off = (size_t)L * 131072 + ((size_t)(kt * 8 + ct) * 64 + lane) * 8;
  *(bf16x8*)&Whi[off] = hi;
  *(bf16x8*)&Wlo[off] = lo;
}

// ---------------- transform: h = x @ W (3-term split-bf16 MFMA) ----------------
// 192 rows/block (3 rt per wave): per-kt staging/barriers amortized over 1.5x rows.

__launch_bounds__(256)
__global__ void transform_mfma(const float* __restrict__ x,
                               const short* __restrict__ Whi, const short* __restrict__ Wlo,
                               const float* __restrict__ a_src, const float* __restrict__ a_dst,
                               unsigned short* __restrict__ hb,
                               float* __restrict__ alphaS, float* __restrict__ alphaD) {
  __shared__ short WhiS[4096];   // one kt of fragments: [(ct*64+lane)*8]
  __shared__ short WloS[4096];
  int tid = threadIdx.x;
  int lane = tid & 63, wid = tid >> 6;
  int l4 = lane & 15, grp = lane >> 4;
  int rbase = blockIdx.x * 192 + wid * 48;

  const float* xr[3];
  #pragma unroll
  for (int rt = 0; rt < 3; ++rt) {
    int R = rbase + rt * 16 + l4;
    xr[rt] = x + (size_t)(R < NN ? R : 0) * 128;
  }

  f32x4 acc[3][8];
  #pragma unroll
  for (int rt = 0; rt < 3; ++rt)
    #pragma unroll
    for (int ct = 0; ct < 8; ++ct) acc[rt][ct] = (f32x4)(0.f);

  for (int kt = 0; kt < 4; ++kt) {
    bf16x8 Ahi[3], Alo[3];
    #pragma unroll
    for (int rt = 0; rt < 3; ++rt) {
      const float* p = xr[rt] + kt * 32 + grp * 8;
      float4 v0 = *(const float4*)p;
      float4 v1 = *(const float4*)(p + 4);
      BV8 hi, lo;
      hi.u.x = cvt_pk_bf16(v0.x, v0.y);
      hi.u.y = cvt_pk_bf16(v0.z, v0.w);
      hi.u.z = cvt_pk_bf16(v1.x, v1.y);
      hi.u.w = cvt_pk_bf16(v1.z, v1.w);
      lo.u.x = cvt_pk_bf16(v0.x - bflo(hi.u.x), v0.y - bfhi(hi.u.x));
      lo.u.y = cvt_pk_bf16(v0.z - bflo(hi.u.y), v0.w - bfhi(hi.u.y));
      lo.u.z = cvt_pk_bf16(v1.x - bflo(hi.u.z), v1.y - bfhi(hi.u.z));
      lo.u.w = cvt_pk_bf16(v1.z - bflo(hi.u.w), v1.w - bfhi(hi.u.w));
      Ahi[rt] = hi.v;
      Alo[rt] = lo.v;
    }
    __syncthreads();   // all waves done reading previous kt staging
    {
      int base = kt * 4096 + tid * 16;
      *(bf16x8*)&WhiS[tid * 16]     = *(const bf16x8*)&Whi[base];
      *(bf16x8*)&WhiS[tid * 16 + 8] = *(const bf16x8*)&Whi[base + 8];
      *(bf16x8*)&WloS[tid * 16]     = *(const bf16x8*)&Wlo[base];
      *(bf16x8*)&WloS[tid * 16 + 8] = *(const bf16x8*)&Wlo[base + 8];
    }
    __syncthreads();
    #pragma unroll
    for (int ct = 0; ct < 8; ++ct) {
      bf16x8 bh = *(const bf16x8*)&WhiS[(ct * 64 + lane) * 8];
      bf16x8 bl = *(const bf16x8*)&WloS[(ct * 64 + lane) * 8];
      #pragma unroll
      for (int rt = 0; rt < 3; ++rt) {
        acc[rt][ct] = __builtin_amdgcn_mfma_f32_16x16x32_bf16(Ahi[rt], bh, acc[rt][ct], 0, 0, 0);
        acc[rt][ct] = __builtin_amdgcn_mfma_f32_16x16x32_bf16(Ahi[rt], bl, acc[rt][ct], 0, 0, 0);
        acc[rt][ct] = __builtin_amdgcn_mfma_f32_16x16x32_bf16(Alo[rt], bh, acc[rt][ct], 0, 0, 0);
      }
    }
  }

  float asv[8], adv[8];
  #pragma unroll
  for (int ct = 0; ct < 8; ++ct) { asv[ct] = a_src[ct * 16 + l4]; adv[ct] = a_dst[ct * 16 + l4]; }

  #pragma unroll
  for (int rt = 0; rt < 3; ++rt) {
    #pragma unroll
    for (int reg = 0; reg < 4; ++reg) {
      float ps = 0.f, pd = 0.f;
      #pragma unroll
      for (int ct = 0; ct < 8; ++ct) {
        ps = fmaf(acc[rt][ct][reg], asv[ct], ps);
        pd = fmaf(acc[rt][ct][reg], adv[ct], pd);
      }
      #pragma unroll
      for (int mdl = 1; mdl < 16; mdl <<= 1) {
        ps += __shfl_xor(ps, mdl);
        pd += __shfl_xor(pd, mdl);
      }
      int row = rbase + rt * 16 + grp * 4 + reg;
      if (l4 == 0 && row < NN) { alphaS[row] = ps; alphaD[row] = pd; }
    }
    #pragma unroll
    for (int reg = 0; reg < 4; ++reg) {
      int row = rbase + rt * 16 + grp * 4 + reg;
      if (row < NN) {
        #pragma unroll
        for (int ct = 0; ct < 8; ct += 2) {
          unsigned u = cvt_pk_bf16(acc[rt][ct][reg], acc[rt][ct + 1][reg]);
          hb[(size_t)row * 128 + ct * 16 + l4]       = (unsigned short)u;
          hb[(size_t)row * 128 + (ct + 1) * 16 + l4] = (unsigned short)(u >> 16);
        }
      }
    }
  }
}

// ---------------- aggregation: fused single pass, depth-4 gather pipeline (frozen) ----------------

template<bool RELU>
__launch_bounds__(256)
__global__ void agg_kernel(const unsigned short* __restrict__ hb,
                           const float* __restrict__ alphaS, const float* __restrict__ alphaD,
                           const int* __restrict__ offsets, const int* __restrict__ srcs,
                           const float* __restrict__ bias, float* __restrict__ out) {
  int lane = threadIdx.x & 63;
  int node = (blockIdx.x * 256 + threadIdx.x) >> 6;
  if (node >= NN) return;
  int beg = offsets[node], end = offsets[node + 1];
  float aD = alphaD[node];

  int l4 = lane & 15, grp = lane >> 4;
  float a[8];
  #pragma unroll
  for (int i = 0; i < 8; ++i) a[i] = 0.f;
  float ssum = 0.f;

  for (int j0 = beg; j0 < end; j0 += 64) {
    int j = j0 + lane;
    int cnt = min(64, end - j0);
    int s = 0; float t = 0.f;
    if (j < end) {
      int sv = srcs[j];
      float e = alphaS[sv] + aD;
      e = (e >= 0.f) ? e : 0.2f * e;
      t = __expf(e);
      s = sv;
    }
    ssum += t;
    for (int jj = 0; jj < cnt; jj += 16) {
      int eA = jj + grp;
      int eB = eA + 4, eC = eA + 8, eD = eA + 12;
      int svA = __shfl(s, eA); float tA = __shfl(t, eA);
      int svB = __shfl(s, eB); float tB = __shfl(t, eB);
      int svC = __shfl(s, eC); float tC = __shfl(t, eC);
      int svD = __shfl(s, eD); float tD = __shfl(t, eD);
      if (tA > 0.f) {
        uint4 h0 = *(const uint4*)&hb[(size_t)svA * 128 + l4 * 8];
        uint4 h1 = *(const uint4*)&hb[(size_t)svB * 128 + l4 * 8];
        a[0] = fmaf(tA, __uint_as_float(h0.x << 16),         a[0]);
        a[1] = fmaf(tA, __uint_as_float(h0.x & 0xffff0000u), a[1]);
        a[2] = fmaf(tA, __uint_as_float(h0.y << 16),         a[2]);
        a[3] = fmaf(tA, __uint_as_float(h0.y & 0xffff0000u), a[3]);
        a[4] = fmaf(tA, __uint_as_float(h0.z << 16),         a[4]);
        a[5] = fmaf(tA, __uint_as_float(h0.z & 0xffff0000u), a[5]);
        a[6] = fmaf(tA, __uint_as_float(h0.w << 16),         a[6]);
        a[7] = fmaf(tA, __uint_as_float(h0.w & 0xffff0000u), a[7]);
        a[0] = fmaf(tB, __uint_as_float(h1.x << 16),         a[0]);
        a[1] = fmaf(tB, __uint_as_float(h1.x & 0xffff0000u), a[1]);
        a[2] = fmaf(tB, __uint_as_float(h1.y << 16),         a[2]);
        a[3] = fmaf(tB, __uint_as_float(h1.y & 0xffff0000u), a[3]);
        a[4] = fmaf(tB, __uint_as_float(h1.z << 16),         a[4]);
        a[5] = fmaf(tB, __uint_as_float(h1.z & 0xffff0000u), a[5]);
        a[6] = fmaf(tB, __uint_as_float(h1.w << 16),         a[6]);
        a[7] = fmaf(tB, __uint_as_float(h1.w & 0xffff0000u), a[7]);
      }
      if (tC > 0.f) {
        uint4 h2 = *(const uint4*)&hb[(size_t)svC * 128 + l4 * 8];
        uint4 h3 = *(const uint4*)&hb[(size_t)svD * 128 + l4 * 8];
        a[0] = fmaf(tC, __uint_as_float(h2.x << 16),         a[0]);
        a[1] = fmaf(tC, __uint_as_float(h2.x & 0xffff0000u), a[1]);
        a[2] = fmaf(tC, __uint_as_float(h2.y << 16),         a[2]);
        a[3] = fmaf(tC, __uint_as_float(h2.y & 0xffff0000u), a[3]);
        a[4] = fmaf(tC, __uint_as_float(h2.z << 16),         a[4]);
        a[5] = fmaf(tC, __uint_as_float(h2.z & 0xffff0000u), a[5]);
        a[6] = fmaf(tC, __uint_as_float(h2.w << 16),         a[6]);
        a[7] = fmaf(tC, __uint_as_float(h2.w & 0xffff0000u), a[7]);
        a[0] = fmaf(tD, __uint_as_float(h3.x << 16),         a[0]);
        a[1] = fmaf(tD, __uint_as_float(h3.x & 0xffff0000u), a[1]);
        a[2] = fmaf(tD, __uint_as_float(h3.y << 16),         a[2]);
        a[3] = fmaf(tD, __uint_as_float(h3.y & 0xffff0000u), a[3]);
        a[4] = fmaf(tD, __uint_as_float(h3.z << 16),         a[4]);
        a[5] = fmaf(tD, __uint_as_float(h3.z & 0xffff0000u), a[5]);
        a[6] = fmaf(tD, __uint_as_float(h3.w << 16),         a[6]);
        a[7] = fmaf(tD, __uint_as_float(h3.w & 0xffff0000u), a[7]);
      }
    }
  }
  #pragma unroll
  for (int d2 = 1; d2 < 64; d2 <<= 1) ssum += __shfl_xor(ssum, d2);
  float inv = 1.f / ssum;

  #pragma unroll
  for (int i = 0; i < 8; ++i) {
    a[i] += __shfl_xor(a[i], 16);
    a[i] += __shfl_xor(a[i], 32);
  }
  if (grp == 0) {
    float4 b0 = *(const float4*)&bias[l4 * 8];
    float4 b1 = *(const float4*)&bias[l4 * 8 + 4];
    float4 o0 = {fmaf(a[0], inv, b0.x), fmaf(a[1], inv, b0.y),
                 fmaf(a[2], inv, b0.z), fmaf(a[3], inv, b0.w)};
    float4 o1 = {fmaf(a[4], inv, b1.x), fmaf(a[5], inv, b1.y),
                 fmaf(a[6], inv, b1.z), fmaf(a[7], inv, b1.w)};
    if (RELU) {
      o0.x = fmaxf(o0.x, 0.f); o0.y = fmaxf(o0.y, 0.f);
      o0.z = fmaxf(o0.z, 0.f); o0.w = fmaxf(o0.w, 0.f);
      o1.x = fmaxf(o1.x, 0.f); o1.y = fmaxf(o1.y, 0.f);
      o1.z = fmaxf(o1.z, 0.f); o1.w = fmaxf(o1.w, 0.f);
    }
    *(float4*)&out[(size_t)node * 128 + l4 * 8]     = o0;
    *(float4*)&out[(size_t)node * 128 + l4 * 8 + 4] = o1;
  }
}

// ---------------- launch ----------------

extern "C" void kernel_launch(void* const* d_in, const int* in_sizes, int n_in,
                              void* d_out, int out_size, void* d_ws, size_t ws_size,
                              hipStream_t stream) {
  const float* x   = (const float*)d_in[0];
  const int*   ei  = (const int*)d_in[1];
  const float* W0  = (const float*)d_in[2];
  const float* as0 = (const float*)d_in[3];
  const float* ad0 = (const float*)d_in[4];
  const float* b0  = (const float*)d_in[5];
  const float* W1  = (const float*)d_in[6];
  const float* as1 = (const float*)d_in[7];
  const float* ad1 = (const float*)d_in[8];
  const float* b1  = (const float*)d_in[9];
  const float* W2  = (const float*)d_in[10];
  const float* as2 = (const float*)d_in[11];
  const float* ad2 = (const float*)d_in[12];
  const float* b2  = (const float*)d_in[13];
  float* out = (float*)d_out;

  unsigned* pairs = (unsigned*)d_ws;                           // E (4B packed)
  short*    Whi   = (short*)(pairs + EE);                      // 3*131072
  short*    Wlo   = Whi + 3 * 131072;                          // 3*131072
  unsigned short* hb = (unsigned short*)(Wlo + 3 * 131072);    // N*128
  float* alphaS = (float*)(hb + (size_t)NN * 128);             // N
  float* alphaD = alphaS + NN;                                 // N
  int*   offsets = (int*)(alphaD + NN);                        // N+1
  int*   srcs    = offsets + NN + 1;                           // E+N
  int*   bcnt    = srcs + EE + NN;                             // NB*16 (padded)
  int*   bfill   = bcnt + NB * 16;                             // NB*16
  int*   bOffC   = bfill + NB * 16;                            // NB

  const int cgrid = (EE + CHUNK - 1) / CHUNK;   // 782

  prep_w3<<<24, 256, 0, stream>>>(W0, W1, W2, Whi, Wlo);
  zero_aux<<<(NB * 16 + 255) / 256, 256, 0, stream>>>(bcnt, bfill);
  bucket_hist<<<cgrid, 256, 0, stream>>>(ei + EE, bcnt);
  bucket_scan<<<1, 256, 0, stream>>>(bcnt, bOffC, offsets);
  bucket_scatter<<<cgrid, 256, 0, stream>>>(ei, bOffC, bfill, pairs);
  build_csr<<<NB, 256, 0, stream>>>(pairs, bOffC, bcnt, offsets, srcs);

  const int tgrid = (NN + 191) / 192;   // 521
  const int agrid = (NN + 3) / 4;

  transform_mfma<<<tgrid, 256, 0, stream>>>(x, Whi, Wlo, as0, ad0, hb, alphaS, alphaD);
  agg_kernel<true><<<agrid, 256, 0, stream>>>(hb, alphaS, alphaD, offsets, srcs, b0, out);

  transform_mfma<<<tgrid, 256, 0, stream>>>(out, Whi + 131072, Wlo + 131072, as1, ad1, hb, alphaS, alphaD);
  agg_kernel<true><<<agrid, 256, 0, stream>>>(hb, alphaS, alphaD, offsets, srcs, b1, out);

  transform_mfma<<<tgrid, 256, 0, stream>>>(out, Whi + 262144, Wlo + 262144, as2, ad2, hb, alphaS, alphaD);
  agg_kernel<false><<<agrid, 256, 0, stream>>>(hb, alphaS, alphaD, offsets, srcs, b2, out);
}

// Round 12
// 358.258 us; speedup vs baseline: 1.1109x; 1.1109x over previous
//
#include <hip/hip_runtime.h>

#define NN 100000
#define EE 1600000
#define NB 391          // buckets of 256 dst nodes: ceil(100000/256)
#define CHUNK 2048

typedef __attribute__((ext_vector_type(8))) short bf16x8;
typedef __attribute__((ext_vector_type(4))) float f32x4;

union BV8 { bf16x8 v; uint4 u; };

static __device__ __forceinline__ unsigned short f2bf(float f) {
  unsigned u = __float_as_uint(f);
  u += 0x7fffu + ((u >> 16) & 1u);   // round-to-nearest-even
  return (unsigned short)(u >> 16);
}
static __device__ __forceinline__ float bf2f(unsigned short s) {
  return __uint_as_float(((unsigned)s) << 16);
}
// HW packed f32->bf16 (no builtin on gfx950)
static __device__ __forceinline__ unsigned cvt_pk_bf16(float a, float b) {
  unsigned r;
  asm("v_cvt_pk_bf16_f32 %0, %1, %2" : "=v"(r) : "v"(a), "v"(b));
  return r;
}
static __device__ __forceinline__ float bflo(unsigned u) { return __uint_as_float(u << 16); }
static __device__ __forceinline__ float bfhi(unsigned u) { return __uint_as_float(u & 0xffff0000u); }

// ---------------- CSR build: two-level counting sort ----------------

__global__ void zero_aux(int* __restrict__ bcnt, int* __restrict__ bfill) {
  int i = blockIdx.x * 256 + threadIdx.x;
  if (i < NB * 16) { bcnt[i] = 0; bfill[i] = 0; }
}

__launch_bounds__(256)
__global__ void bucket_hist(const int* __restrict__ dst, int* __restrict__ bcnt) {
  __shared__ int hist[NB];
  int tid = threadIdx.x;
  for (int i = tid; i < NB; i += 256) hist[i] = 0;
  __syncthreads();
  int e0 = blockIdx.x * CHUNK;
  int n = min(CHUNK, EE - e0);
  for (int i = tid; i < n; i += 256) atomicAdd(&hist[dst[e0 + i] >> 8], 1);
  __syncthreads();
  for (int i = tid; i < NB; i += 256) {
    int c = hist[i];
    if (c) atomicAdd(&bcnt[i * 16], c);
  }
}

__launch_bounds__(256)
__global__ void bucket_scan(const int* __restrict__ bcnt, int* __restrict__ bOffC,
                            int* __restrict__ offsets) {
  __shared__ int wpart[4];
  __shared__ int carryS;
  int tid = threadIdx.x, lane = tid & 63, w = tid >> 6;
  if (tid == 0) carryS = 0;
  __syncthreads();
  for (int base = 0; base < NB; base += 256) {
    int i = base + tid;
    int v = (i < NB) ? bcnt[i * 16] : 0;
    int x = v;
    #pragma unroll
    for (int d = 1; d < 64; d <<= 1) { int y = __shfl_up(x, d); if (lane >= d) x += y; }
    if (lane == 63) wpart[w] = x;
    __syncthreads();
    int wbase = 0;
    #pragma unroll
    for (int k = 0; k < 3; ++k) if (k < w) wbase += wpart[k];
    int tot = wpart[0] + wpart[1] + wpart[2] + wpart[3];
    int carry = carryS;
    if (i < NB) bOffC[i] = carry + wbase + x - v;
    __syncthreads();
    if (tid == 0) carryS = carry + tot;
    __syncthreads();
  }
  if (tid == 0) offsets[NN] = EE + NN;
}

__launch_bounds__(256)
__global__ void bucket_scatter(const int* __restrict__ ei, const int* __restrict__ bOffC,
                               int* __restrict__ bfill, long long* __restrict__ pairs) {
  __shared__ int hist[NB];
  __shared__ int lofs[NB];
  __shared__ int resv[NB];
  __shared__ long long stage[CHUNK];
  __shared__ int wpart[4];
  int tid = threadIdx.x, lane = tid & 63, w = tid >> 6;
  int e0 = blockIdx.x * CHUNK;
  int n = min(CHUNK, EE - e0);
  for (int i = tid; i < NB; i += 256) hist[i] = 0;
  __syncthreads();

  int s[8], d[8], lp[8], bk[8];
  #pragma unroll
  for (int q = 0; q < 8; ++q) {
    int i = q * 256 + tid;
    if (i < n) {
      s[q] = ei[e0 + i];
      d[q] = ei[EE + e0 + i];
      bk[q] = d[q] >> 8;
      lp[q] = atomicAdd(&hist[bk[q]], 1);
    }
  }
  __syncthreads();

  int carry = 0;
  for (int base = 0; base < NB; base += 256) {
    int i = base + tid;
    int v = (i < NB) ? hist[i] : 0;
    int x = v;
    #pragma unroll
    for (int dd = 1; dd < 64; dd <<= 1) { int y = __shfl_up(x, dd); if (lane >= dd) x += y; }
    if (lane == 63) wpart[w] = x;
    __syncthreads();
    int wbase = 0;
    #pragma unroll
    for (int k = 0; k < 3; ++k) if (k < w) wbase += wpart[k];
    int tot = wpart[0] + wpart[1] + wpart[2] + wpart[3];
    if (i < NB) lofs[i] = carry + wbase + x - v;
    __syncthreads();
    carry += tot;
  }

  #pragma unroll
  for (int q = 0; q < 8; ++q) {
    int i = q * 256 + tid;
    if (i < n) stage[lofs[bk[q]] + lp[q]] = ((long long)d[q] << 32) | (unsigned)s[q];
  }
  for (int b = tid; b < NB; b += 256) {
    int c = hist[b];
    resv[b] = c ? atomicAdd(&bfill[b * 16], c) : 0;
  }
  __syncthreads();
  for (int i = tid; i < n; i += 256) {
    long long pd = stage[i];
    int dd = (int)(pd >> 32);
    int b = dd >> 8;
    pairs[(size_t)bOffC[b] + resv[b] + (i - lofs[b])] = pd;
  }
}

__launch_bounds__(256)
__global__ void build_csr(const long long* __restrict__ pairs, const int* __restrict__ bOffC,
                          const int* __restrict__ bcnt, int* __restrict__ offsets,
                          int* __restrict__ srcs) {
  __shared__ int deg[256];
  __shared__ int intra[256];
  __shared__ int fil[256];
  __shared__ int wpart[4];
  int b = blockIdx.x, tid = threadIdx.x;
  int n0 = b << 8;
  int nodes = min(256, NN - n0);
  int ecnt = bcnt[b * 16];
  size_t pbase = (size_t)bOffC[b];
  int cbase = bOffC[b] + n0;
  deg[tid] = 0; fil[tid] = 0;
  __syncthreads();
  for (int i = tid; i < ecnt; i += 256) {
    int dd = (int)(pairs[pbase + i] >> 32);
    atomicAdd(&deg[dd - n0], 1);
  }
  __syncthreads();
  int v = (tid < nodes) ? deg[tid] + 1 : 0;
  int lane = tid & 63, w = tid >> 6;
  int x = v;
  #pragma unroll
  for (int dd = 1; dd < 64; dd <<= 1) { int y = __shfl_up(x, dd); if (lane >= dd) x += y; }
  if (lane == 63) wpart[w] = x;
  __syncthreads();
  int wbase = 0;
  #pragma unroll
  for (int k = 0; k < 3; ++k) if (k < w) wbase += wpart[k];
  int excl = wbase + x - v;
  if (tid < nodes) { intra[tid] = excl; offsets[n0 + tid] = cbase + excl; }
  __syncthreads();
  for (int i = tid; i < ecnt; i += 256) {
    long long pd = pairs[pbase + i];
    int dd = (int)(pd >> 32), ss = (int)pd;
    int ln = dd - n0;
    int p = atomicAdd(&fil[ln], 1);
    srcs[cbase + intra[ln] + p] = ss;
  }
  __syncthreads();
  if (tid < nodes) srcs[cbase + intra[tid] + deg[tid]] = n0 + tid;
}

// ---------------- W prep: all 3 layers, fragment-ordered bf16 hi/lo ----------------

__global__ void prep_w3(const float* __restrict__ Wa, const float* __restrict__ Wb,
                        const float* __restrict__ Wc, short* __restrict__ Whi,
                        short* __restrict__ Wlo) {
  int t = blockIdx.x * 256 + threadIdx.x;   // 24 blocks = 6144 threads
  int L = t >> 11;                          // layer
  int tt = t & 2047;
  const float* W = (L == 0) ? Wa : (L == 1) ? Wb : Wc;
  int lane = tt & 63, ct = (tt >> 6) & 7, kt = tt >> 9;
  int l4 = lane & 15, grp = lane >> 4;
  int c = ct * 16 + l4;
  int k0 = kt * 32 + grp * 8;
  bf16x8 hi, lo;
  #pragma unroll
  for (int i = 0; i < 8; ++i) {
    float w = W[(k0 + i) * 128 + c];
    unsigned short h = f2bf(w);
    hi[i] = (short)h;
    lo[i] = (short)f2bf(w - bf2f(h));
  }
  size_t off = (size_t)L * 131072 + ((size_t)(kt * 8 + ct) * 64 + lane) * 8;
  *(bf16x8*)&Whi[off] = hi;
  *(bf16x8*)&Wlo[off] = lo;
}

// ---------------- transform: h = x @ W (3-term split-bf16 MFMA) ----------------
// 128 rows/block; double-buffered W staging (stage kt+1 under kt's MFMA, 1 barrier/kt).

__launch_bounds__(256, 2)
__global__ void transform_mfma(const float* __restrict__ x,
                               const short* __restrict__ Whi, const short* __restrict__ Wlo,
                               const float* __restrict__ a_src, const float* __restrict__ a_dst,
                               unsigned short* __restrict__ hb,
                               float* __restrict__ alphaS, float* __restrict__ alphaD) {
  __shared__ short WhiS[2][4096];   // double-buffered kt fragments: [(ct*64+lane)*8]
  __shared__ short WloS[2][4096];
  int tid = threadIdx.x;
  int lane = tid & 63, wid = tid >> 6;
  int l4 = lane & 15, grp = lane >> 4;
  int rbase = blockIdx.x * 128 + wid * 32;

  const float* xr[2];
  #pragma unroll
  for (int rt = 0; rt < 2; ++rt) {
    int R = rbase + rt * 16 + l4;
    xr[rt] = x + (size_t)(R < NN ? R : 0) * 128;
  }

  f32x4 acc[2][8];
  #pragma unroll
  for (int rt = 0; rt < 2; ++rt)
    #pragma unroll
    for (int ct = 0; ct < 8; ++ct) acc[rt][ct] = (f32x4)(0.f);

  // prologue: stage kt=0 into buffer 0
  {
    int base = tid * 16;
    *(bf16x8*)&WhiS[0][tid * 16]     = *(const bf16x8*)&Whi[base];
    *(bf16x8*)&WhiS[0][tid * 16 + 8] = *(const bf16x8*)&Whi[base + 8];
    *(bf16x8*)&WloS[0][tid * 16]     = *(const bf16x8*)&Wlo[base];
    *(bf16x8*)&WloS[0][tid * 16 + 8] = *(const bf16x8*)&Wlo[base + 8];
  }
  __syncthreads();

  #pragma unroll
  for (int kt = 0; kt < 4; ++kt) {
    int cur = kt & 1;
    // A-operand convert for this kt
    bf16x8 Ahi[2], Alo[2];
    #pragma unroll
    for (int rt = 0; rt < 2; ++rt) {
      const float* p = xr[rt] + kt * 32 + grp * 8;
      float4 v0 = *(const float4*)p;
      float4 v1 = *(const float4*)(p + 4);
      BV8 hi, lo;
      hi.u.x = cvt_pk_bf16(v0.x, v0.y);
      hi.u.y = cvt_pk_bf16(v0.z, v0.w);
      hi.u.z = cvt_pk_bf16(v1.x, v1.y);
      hi.u.w = cvt_pk_bf16(v1.z, v1.w);
      lo.u.x = cvt_pk_bf16(v0.x - bflo(hi.u.x), v0.y - bfhi(hi.u.x));
      lo.u.y = cvt_pk_bf16(v0.z - bflo(hi.u.y), v0.w - bfhi(hi.u.y));
      lo.u.z = cvt_pk_bf16(v1.x - bflo(hi.u.z), v1.y - bfhi(hi.u.z));
      lo.u.w = cvt_pk_bf16(v1.z - bflo(hi.u.w), v1.w - bfhi(hi.u.w));
      Ahi[rt] = hi.v;
      Alo[rt] = lo.v;
    }
    // stage kt+1 into the other buffer (overlaps with this kt's MFMAs;
    // safe: buf cur^1's readers finished at the previous barrier)
    if (kt < 3) {
      int base = (kt + 1) * 4096 + tid * 16;
      *(bf16x8*)&WhiS[cur ^ 1][tid * 16]     = *(const bf16x8*)&Whi[base];
      *(bf16x8*)&WhiS[cur ^ 1][tid * 16 + 8] = *(const bf16x8*)&Whi[base + 8];
      *(bf16x8*)&WloS[cur ^ 1][tid * 16]     = *(const bf16x8*)&Wlo[base];
      *(bf16x8*)&WloS[cur ^ 1][tid * 16 + 8] = *(const bf16x8*)&Wlo[base + 8];
    }
    #pragma unroll
    for (int ct = 0; ct < 8; ++ct) {
      bf16x8 bh = *(const bf16x8*)&WhiS[cur][(ct * 64 + lane) * 8];
      bf16x8 bl = *(const bf16x8*)&WloS[cur][(ct * 64 + lane) * 8];
      #pragma unroll
      for (int rt = 0; rt < 2; ++rt) {
        acc[rt][ct] = __builtin_amdgcn_mfma_f32_16x16x32_bf16(Ahi[rt], bh, acc[rt][ct], 0, 0, 0);
        acc[rt][ct] = __builtin_amdgcn_mfma_f32_16x16x32_bf16(Ahi[rt], bl, acc[rt][ct], 0, 0, 0);
        acc[rt][ct] = __builtin_amdgcn_mfma_f32_16x16x32_bf16(Alo[rt], bh, acc[rt][ct], 0, 0, 0);
      }
    }
    __syncthreads();
  }

  float asv[8], adv[8];
  #pragma unroll
  for (int ct = 0; ct < 8; ++ct) { asv[ct] = a_src[ct * 16 + l4]; adv[ct] = a_dst[ct * 16 + l4]; }

  #pragma unroll
  for (int rt = 0; rt < 2; ++rt) {
    #pragma unroll
    for (int reg = 0; reg < 4; ++reg) {
      float ps = 0.f, pd = 0.f;
      #pragma unroll
      for (int ct = 0; ct < 8; ++ct) {
        ps = fmaf(acc[rt][ct][reg], asv[ct], ps);
        pd = fmaf(acc[rt][ct][reg], adv[ct], pd);
      }
      #pragma unroll
      for (int mdl = 1; mdl < 16; mdl <<= 1) {
        ps += __shfl_xor(ps, mdl);
        pd += __shfl_xor(pd, mdl);
      }
      int row = rbase + rt * 16 + grp * 4 + reg;
      if (l4 == 0 && row < NN) { alphaS[row] = ps; alphaD[row] = pd; }
    }
    #pragma unroll
    for (int reg = 0; reg < 4; ++reg) {
      int row = rbase + rt * 16 + grp * 4 + reg;
      if (row < NN) {
        #pragma unroll
        for (int ct = 0; ct < 8; ct += 2) {
          unsigned u = cvt_pk_bf16(acc[rt][ct][reg], acc[rt][ct + 1][reg]);
          hb[(size_t)row * 128 + ct * 16 + l4]       = (unsigned short)u;
          hb[(size_t)row * 128 + (ct + 1) * 16 + l4] = (unsigned short)(u >> 16);
        }
      }
    }
  }
}

// ---------------- aggregation: fused single pass, depth-4 gather pipeline (frozen) ----------------

template<bool RELU>
__launch_bounds__(256)
__global__ void agg_kernel(const unsigned short* __restrict__ hb,
                           const float* __restrict__ alphaS, const float* __restrict__ alphaD,
                           const int* __restrict__ offsets, const int* __restrict__ srcs,
                           const float* __restrict__ bias, float* __restrict__ out) {
  int lane = threadIdx.x & 63;
  int node = (blockIdx.x * 256 + threadIdx.x) >> 6;
  if (node >= NN) return;
  int beg = offsets[node], end = offsets[node + 1];
  float aD = alphaD[node];

  int l4 = lane & 15, grp = lane >> 4;
  float a[8];
  #pragma unroll
  for (int i = 0; i < 8; ++i) a[i] = 0.f;
  float ssum = 0.f;

  for (int j0 = beg; j0 < end; j0 += 64) {
    int j = j0 + lane;
    int cnt = min(64, end - j0);
    int s = 0; float t = 0.f;
    if (j < end) {
      int sv = srcs[j];
      float e = alphaS[sv] + aD;
      e = (e >= 0.f) ? e : 0.2f * e;
      t = __expf(e);
      s = sv;
    }
    ssum += t;
    for (int jj = 0; jj < cnt; jj += 16) {
      int eA = jj + grp;
      int eB = eA + 4, eC = eA + 8, eD = eA + 12;
      int svA = __shfl(s, eA); float tA = __shfl(t, eA);
      int svB = __shfl(s, eB); float tB = __shfl(t, eB);
      int svC = __shfl(s, eC); float tC = __shfl(t, eC);
      int svD = __shfl(s, eD); float tD = __shfl(t, eD);
      if (tA > 0.f) {
        uint4 h0 = *(const uint4*)&hb[(size_t)svA * 128 + l4 * 8];
        uint4 h1 = *(const uint4*)&hb[(size_t)svB * 128 + l4 * 8];
        a[0] = fmaf(tA, __uint_as_float(h0.x << 16),         a[0]);
        a[1] = fmaf(tA, __uint_as_float(h0.x & 0xffff0000u), a[1]);
        a[2] = fmaf(tA, __uint_as_float(h0.y << 16),         a[2]);
        a[3] = fmaf(tA, __uint_as_float(h0.y & 0xffff0000u), a[3]);
        a[4] = fmaf(tA, __uint_as_float(h0.z << 16),         a[4]);
        a[5] = fmaf(tA, __uint_as_float(h0.z & 0xffff0000u), a[5]);
        a[6] = fmaf(tA, __uint_as_float(h0.w << 16),         a[6]);
        a[7] = fmaf(tA, __uint_as_float(h0.w & 0xffff0000u), a[7]);
        a[0] = fmaf(tB, __uint_as_float(h1.x << 16),         a[0]);
        a[1] = fmaf(tB, __uint_as_float(h1.x & 0xffff0000u), a[1]);
        a[2] = fmaf(tB, __uint_as_float(h1.y << 16),         a[2]);
        a[3] = fmaf(tB, __uint_as_float(h1.y & 0xffff0000u), a[3]);
        a[4] = fmaf(tB, __uint_as_float(h1.z << 16),         a[4]);
        a[5] = fmaf(tB, __uint_as_float(h1.z & 0xffff0000u), a[5]);
        a[6] = fmaf(tB, __uint_as_float(h1.w << 16),         a[6]);
        a[7] = fmaf(tB, __uint_as_float(h1.w & 0xffff0000u), a[7]);
      }
      if (tC > 0.f) {
        uint4 h2 = *(const uint4*)&hb[(size_t)svC * 128 + l4 * 8];
        uint4 h3 = *(const uint4*)&hb[(size_t)svD * 128 + l4 * 8];
        a[0] = fmaf(tC, __uint_as_float(h2.x << 16),         a[0]);
        a[1] = fmaf(tC, __uint_as_float(h2.x & 0xffff0000u), a[1]);
        a[2] = fmaf(tC, __uint_as_float(h2.y << 16),         a[2]);
        a[3] = fmaf(tC, __uint_as_float(h2.y & 0xffff0000u), a[3]);
        a[4] = fmaf(tC, __uint_as_float(h2.z << 16),         a[4]);
        a[5] = fmaf(tC, __uint_as_float(h2.z & 0xffff0000u), a[5]);
        a[6] = fmaf(tC, __uint_as_float(h2.w << 16),         a[6]);
        a[7] = fmaf(tC, __uint_as_float(h2.w & 0xffff0000u), a[7]);
        a[0] = fmaf(tD, __uint_as_float(h3.x << 16),         a[0]);
        a[1] = fmaf(tD, __uint_as_float(h3.x & 0xffff0000u), a[1]);
        a[2] = fmaf(tD, __uint_as_float(h3.y << 16),         a[2]);
        a[3] = fmaf(tD, __uint_as_float(h3.y & 0xffff0000u), a[3]);
        a[4] = fmaf(tD, __uint_as_float(h3.z << 16),         a[4]);
        a[5] = fmaf(tD, __uint_as_float(h3.z & 0xffff0000u), a[5]);
        a[6] = fmaf(tD, __uint_as_float(h3.w << 16),         a[6]);
        a[7] = fmaf(tD, __uint_as_float(h3.w & 0xffff0000u), a[7]);
      }
    }
  }
  #pragma unroll
  for (int d2 = 1; d2 < 64; d2 <<= 1) ssum += __shfl_xor(ssum, d2);
  float inv = 1.f / ssum;

  #pragma unroll
  for (int i = 0; i < 8; ++i) {
    a[i] += __shfl_xor(a[i], 16);
    a[i] += __shfl_xor(a[i], 32);
  }
  if (grp == 0) {
    float4 b0 = *(const float4*)&bias[l4 * 8];
    float4 b1 = *(const float4*)&bias[l4 * 8 + 4];
    float4 o0 = {fmaf(a[0], inv, b0.x), fmaf(a[1], inv, b0.y),
                 fmaf(a[2], inv, b0.z), fmaf(a[3], inv, b0.w)};
    float4 o1 = {fmaf(a[4], inv, b1.x), fmaf(a[5], inv, b1.y),
                 fmaf(a[6], inv, b1.z), fmaf(a[7], inv, b1.w)};
    if (RELU) {
      o0.x = fmaxf(o0.x, 0.f); o0.y = fmaxf(o0.y, 0.f);
      o0.z = fmaxf(o0.z, 0.f); o0.w = fmaxf(o0.w, 0.f);
      o1.x = fmaxf(o1.x, 0.f); o1.y = fmaxf(o1.y, 0.f);
      o1.z = fmaxf(o1.z, 0.f); o1.w = fmaxf(o1.w, 0.f);
    }
    *(float4*)&out[(size_t)node * 128 + l4 * 8]     = o0;
    *(float4*)&out[(size_t)node * 128 + l4 * 8 + 4] = o1;
  }
}

// ---------------- launch ----------------

extern "C" void kernel_launch(void* const* d_in, const int* in_sizes, int n_in,
                              void* d_out, int out_size, void* d_ws, size_t ws_size,
                              hipStream_t stream) {
  const float* x   = (const float*)d_in[0];
  const int*   ei  = (const int*)d_in[1];
  const float* W0  = (const float*)d_in[2];
  const float* as0 = (const float*)d_in[3];
  const float* ad0 = (const float*)d_in[4];
  const float* b0  = (const float*)d_in[5];
  const float* W1  = (const float*)d_in[6];
  const float* as1 = (const float*)d_in[7];
  const float* ad1 = (const float*)d_in[8];
  const float* b1  = (const float*)d_in[9];
  const float* W2  = (const float*)d_in[10];
  const float* as2 = (const float*)d_in[11];
  const float* ad2 = (const float*)d_in[12];
  const float* b2  = (const float*)d_in[13];
  float* out = (float*)d_out;

  long long* pairs = (long long*)d_ws;                         // E (8B-aligned first)
  short* Whi = (short*)(pairs + EE);                           // 3*131072
  short* Wlo = Whi + 3 * 131072;                               // 3*131072
  unsigned short* hb = (unsigned short*)(Wlo + 3 * 131072);    // N*128
  float* alphaS = (float*)(hb + (size_t)NN * 128);             // N
  float* alphaD = alphaS + NN;                                 // N
  int*   offsets = (int*)(alphaD + NN);                        // N+1
  int*   srcs    = offsets + NN + 1;                           // E+N
  int*   bcnt    = srcs + EE + NN;                             // NB*16 (padded)
  int*   bfill   = bcnt + NB * 16;                             // NB*16
  int*   bOffC   = bfill + NB * 16;                            // NB

  const int cgrid = (EE + CHUNK - 1) / CHUNK;   // 782

  prep_w3<<<24, 256, 0, stream>>>(W0, W1, W2, Whi, Wlo);
  zero_aux<<<(NB * 16 + 255) / 256, 256, 0, stream>>>(bcnt, bfill);
  bucket_hist<<<cgrid, 256, 0, stream>>>(ei + EE, bcnt);
  bucket_scan<<<1, 256, 0, stream>>>(bcnt, bOffC, offsets);
  bucket_scatter<<<cgrid, 256, 0, stream>>>(ei, bOffC, bfill, pairs);
  build_csr<<<NB, 256, 0, stream>>>(pairs, bOffC, bcnt, offsets, srcs);

  const int tgrid = (NN + 127) / 128;
  const int agrid = (NN + 3) / 4;

  transform_mfma<<<tgrid, 256, 0, stream>>>(x, Whi, Wlo, as0, ad0, hb, alphaS, alphaD);
  agg_kernel<true><<<agrid, 256, 0, stream>>>(hb, alphaS, alphaD, offsets, srcs, b0, out);

  transform_mfma<<<tgrid, 256, 0, stream>>>(out, Whi + 131072, Wlo + 131072, as1, ad1, hb, alphaS, alphaD);
  agg_kernel<true><<<agrid, 256, 0, stream>>>(hb, alphaS, alphaD, offsets, srcs, b1, out);

  transform_mfma<<<tgrid, 256, 0, stream>>>(out, Whi + 262144, Wlo + 262144, as2, ad2, hb, alphaS, alphaD);
  agg_kernel<false><<<agrid, 256, 0, stream>>>(hb, alphaS, alphaD, offsets, srcs, b2, out);
}